// Round 11
// baseline (247.093 us; speedup 1.0000x reference)
//
#include <hip/hip_runtime.h>

// VQ-VAE vector quantization, MI355X gfx950.
// B=16, C=64, H=W=64 -> N=65536 pixels; K=1024 codes, dim 64.
// NUMERICS (DO NOT CHANGE — r7/r9 passed absmax 0.0 with exactly this):
//   nz/ne: numpy pairwise sum, 8-accumulator unroll, products rounded
//          separately (no fma contraction);
//   dot:   single ascending fp32 fma chain per (pixel,code);
//   d = fl( fl(nz - fl(2*dot)) + ne ); strict-< ascending-k tie-break.
//   ~135 pixels are decided by quantized ties.
//
// Perf history:
//   r7 LDS-broadcast 1px: 161 µs. r8 uniform global: 185 µs.
//   r9 LDS-broadcast 2px: 137 µs = 63 TB/s LDS traffic ~ 90% of the LDS
//      data-path ceiling (broadcast replicates 16 B to every lane).
//   r10 SMEM e + SMEM ne: WRONG indices (absmax 1014). Prime suspect: ne
//      s_load from ws (written by prior dispatch's vector stores, re-poisoned
//      0xAA by harness) served stale through the scalar K$ -> all ne ~ -3e-13
//      -> argmin degenerates. emb itself is harness-written input (same
//      coherence class as kernel args, which ARE read via s_load).
// r11: keep e on the scalar path (s_load_dwordx16 double-buffered into
//      SGPRs), but ne staged through LDS sn[] (r7-style, known good, 512 B).
#define N_PIX   65536
#define CDIM    64
#define KCODES  1024
#define HWSZ    4096          // H*W
#define KCHUNK  128           // codes per argmin block
#define NCHUNK  8             // KCODES / KCHUNK
#define TPB     256

// workspace layout (float-element offsets)
#define OFF_NE   0            // 1024   f32: ||e_k||^2 (numpy pairwise)
#define OFF_MIN  1024         // 65536*8 f32: per-chunk min score
#define OFF_IDX  525312       // 65536*8 i32: per-chunk argmin
#define OFF_LOSS 1049600      // 1 f32: SSE accumulator

// output layout (float-element offsets): z_q | indices | loss
#define OUT_IDX  (N_PIX * CDIM)         // 4194304
#define OUT_LOSS (OUT_IDX + N_PIX)      // 4259840

typedef float sf16 __attribute__((ext_vector_type(16)));

// SMEM load: base in SGPR pair, byte offset in SGPR. Explicit waitcnt ties
// the loaded tuples through "+s" so no use can be scheduled before the wait.
#define SLOAD16(dst, base, off) \
    asm volatile("s_load_dwordx16 %0, %1, %2" : "=s"(dst) : "s"(base), "s"(off))
#define SWAIT2(x, y) asm volatile("s_waitcnt lgkmcnt(0)" : "+s"(x), "+s"(y))

// 16 steps of the ascending-k fma chain from an SGPR 16-tuple
#define FMA16(acc, zb, V) do { \
    acc = fmaf(zr[(zb)+0],  (V)[0],  acc); \
    acc = fmaf(zr[(zb)+1],  (V)[1],  acc); \
    acc = fmaf(zr[(zb)+2],  (V)[2],  acc); \
    acc = fmaf(zr[(zb)+3],  (V)[3],  acc); \
    acc = fmaf(zr[(zb)+4],  (V)[4],  acc); \
    acc = fmaf(zr[(zb)+5],  (V)[5],  acc); \
    acc = fmaf(zr[(zb)+6],  (V)[6],  acc); \
    acc = fmaf(zr[(zb)+7],  (V)[7],  acc); \
    acc = fmaf(zr[(zb)+8],  (V)[8],  acc); \
    acc = fmaf(zr[(zb)+9],  (V)[9],  acc); \
    acc = fmaf(zr[(zb)+10], (V)[10], acc); \
    acc = fmaf(zr[(zb)+11], (V)[11], acc); \
    acc = fmaf(zr[(zb)+12], (V)[12], acc); \
    acc = fmaf(zr[(zb)+13], (V)[13], acc); \
    acc = fmaf(zr[(zb)+14], (V)[14], acc); \
    acc = fmaf(zr[(zb)+15], (V)15[0]*0 + (V)[15], acc); \
} while (0)

// (typo guard: the line above must be exactly (V)[15]; rewritten below)
#undef FMA16
#define FMA16(acc, zb, V) do { \
    acc = fmaf(zr[(zb)+0],  (V)[0],  acc); \
    acc = fmaf(zr[(zb)+1],  (V)[1],  acc); \
    acc = fmaf(zr[(zb)+2],  (V)[2],  acc); \
    acc = fmaf(zr[(zb)+3],  (V)[3],  acc); \
    acc = fmaf(zr[(zb)+4],  (V)[4],  acc); \
    acc = fmaf(zr[(zb)+5],  (V)[5],  acc); \
    acc = fmaf(zr[(zb)+6],  (V)[6],  acc); \
    acc = fmaf(zr[(zb)+7],  (V)[7],  acc); \
    acc = fmaf(zr[(zb)+8],  (V)[8],  acc); \
    acc = fmaf(zr[(zb)+9],  (V)[9],  acc); \
    acc = fmaf(zr[(zb)+10], (V)[10], acc); \
    acc = fmaf(zr[(zb)+11], (V)[11], acc); \
    acc = fmaf(zr[(zb)+12], (V)[12], acc); \
    acc = fmaf(zr[(zb)+13], (V)[13], acc); \
    acc = fmaf(zr[(zb)+14], (V)[14], acc); \
    acc = fmaf(zr[(zb)+15], (V)[15], acc); \
} while (0)

// ---------------- Kernel A: ||e_k||^2 (numpy order), zero loss --------------
__global__ void vq_prep(const float* __restrict__ emb, float* __restrict__ ws) {
#pragma clang fp contract(off)
    int k = blockIdx.x * blockDim.x + threadIdx.x;   // 1024 threads
    if (k == 0) ws[OFF_LOSS] = 0.0f;
    if (k >= KCODES) return;
    const float* e = emb + k * CDIM;
    float r0 = e[0]*e[0], r1 = e[1]*e[1], r2 = e[2]*e[2], r3 = e[3]*e[3];
    float r4 = e[4]*e[4], r5 = e[5]*e[5], r6 = e[6]*e[6], r7 = e[7]*e[7];
    for (int i = 8; i < CDIM; i += 8) {
        r0 = r0 + e[i+0]*e[i+0]; r1 = r1 + e[i+1]*e[i+1];
        r2 = r2 + e[i+2]*e[i+2]; r3 = r3 + e[i+3]*e[i+3];
        r4 = r4 + e[i+4]*e[i+4]; r5 = r5 + e[i+5]*e[i+5];
        r6 = r6 + e[i+6]*e[i+6]; r7 = r7 + e[i+7]*e[i+7];
    }
    ws[OFF_NE + k] = ((r0 + r1) + (r2 + r3)) + ((r4 + r5) + (r6 + r7));
}

// exact numpy pairwise ||.||^2 from registers
__device__ __forceinline__ float np_nz(const float* zr) {
#pragma clang fp contract(off)
    float r0 = zr[0]*zr[0], r1 = zr[1]*zr[1], r2 = zr[2]*zr[2], r3 = zr[3]*zr[3];
    float r4 = zr[4]*zr[4], r5 = zr[5]*zr[5], r6 = zr[6]*zr[6], r7 = zr[7]*zr[7];
#pragma unroll
    for (int i = 8; i < CDIM; i += 8) {
        r0 = r0 + zr[i+0]*zr[i+0]; r1 = r1 + zr[i+1]*zr[i+1];
        r2 = r2 + zr[i+2]*zr[i+2]; r3 = r3 + zr[i+3]*zr[i+3];
        r4 = r4 + zr[i+4]*zr[i+4]; r5 = r5 + zr[i+5]*zr[i+5];
        r6 = r6 + zr[i+6]*zr[i+6]; r7 = r7 + zr[i+7]*zr[i+7];
    }
    return ((r0 + r1) + (r2 + r3)) + ((r4 + r5) + (r6 + r7));
}

// ---------------- Kernel B: split-K argmin, SGPR e + LDS ne -----------------
// grid = (N_PIX/TPB, NCHUNK); block = TPB. One pixel per thread.
__global__ __launch_bounds__(TPB) void vq_argmin(const float* __restrict__ z,
                                                 const float* __restrict__ ws,
                                                 const float* __restrict__ emb,
                                                 float* __restrict__ cmin,
                                                 int* __restrict__ cidx) {
#pragma clang fp contract(off)
    __shared__ float sn[KCHUNK];          // ne via vector path (known good)

    const int chunk = blockIdx.y;
    const int k0 = chunk * KCHUNK;

    if (threadIdx.x < KCHUNK) sn[threadIdx.x] = ws[OFF_NE + k0 + threadIdx.x];

    const int p  = blockIdx.x * TPB + threadIdx.x;
    const int b  = p >> 12;
    const int hw = p & (HWSZ - 1);

    // z[b, c, hw]: lanes consecutive in hw -> coalesced
    const float* zp = z + ((size_t)(b * CDIM) << 12) + hw;
    float zr[CDIM];
#pragma unroll
    for (int c = 0; c < CDIM; ++c) zr[c] = zp[(size_t)c << 12];

    const float nz = np_nz(zr);

    __syncthreads();

    const unsigned long long ebase =
        (unsigned long long)(const void*)(emb + (size_t)k0 * CDIM);

    sf16 A0, A1, B0, B1;   // SGPR stage buffers: 16 k-values x 2 codes, x2

    // prime stage 0 of pair kk=0 (codes k0, k0+1; floats [0:16))
    {
        unsigned int o0 = 0u, o1 = 256u;
        SLOAD16(A0, ebase, o0);
        SLOAD16(A1, ebase, o1);
    }

    float best = 3.4e38f;
    int   bi   = k0;
    for (int kk = 0; kk < KCHUNK; kk += 2) {
        const unsigned int po  = (unsigned int)kk * 256u;        // pair byte offset
        const unsigned int npo = (unsigned int)((kk + 2) & (KCHUNK - 1)) * 256u;
        float a0 = 0.f, a1 = 0.f;

        // stage 0: k[0:16)  — consume A, prefetch B(k[16:32))
        SWAIT2(A0, A1);
        SLOAD16(B0, ebase, po + 64u);
        SLOAD16(B1, ebase, po + 320u);
        FMA16(a0, 0, A0);
        FMA16(a1, 0, A1);

        // stage 1: k[16:32) — consume B, prefetch A(k[32:48))
        SWAIT2(B0, B1);
        SLOAD16(A0, ebase, po + 128u);
        SLOAD16(A1, ebase, po + 384u);
        FMA16(a0, 16, B0);
        FMA16(a1, 16, B1);

        // stage 2: k[32:48) — consume A, prefetch B(k[48:64))
        SWAIT2(A0, A1);
        SLOAD16(B0, ebase, po + 192u);
        SLOAD16(B1, ebase, po + 448u);
        FMA16(a0, 32, A0);
        FMA16(a1, 32, A1);

        // stage 3: k[48:64) — consume B, prefetch next pair's stage 0
        SWAIT2(B0, B1);
        SLOAD16(A0, ebase, npo);
        SLOAD16(A1, ebase, npo + 256u);
        FMA16(a0, 48, B0);
        FMA16(a1, 48, B1);

        // d = fl( fl(nz - 2*a) + ne ): exact numpy rounding sequence
        float d0 = (nz - 2.0f * a0) + sn[kk];
        float d1 = (nz - 2.0f * a1) + sn[kk + 1];
        if (d0 < best) { best = d0; bi = k0 + kk; }       // strict <, ascending k
        if (d1 < best) { best = d1; bi = k0 + kk + 1; }
    }
    cmin[(p << 3) + chunk] = best;
    cidx[(p << 3) + chunk] = bi;
}

// ---------------- Kernel C: reduce chunks, gather z_q, loss -----------------
__global__ __launch_bounds__(TPB) void vq_finalize(const float* __restrict__ z,
                                                   const float* __restrict__ emb,
                                                   const float* __restrict__ cmin,
                                                   const int* __restrict__ cidx,
                                                   float* __restrict__ out,
                                                   float* __restrict__ loss_acc) {
    const int p = blockIdx.x * TPB + threadIdx.x;

    // ascending-chunk strict < keeps the earliest (lowest-k) minimum
    float best = cmin[p << 3];
    int   bi   = cidx[p << 3];
#pragma unroll
    for (int ch = 1; ch < NCHUNK; ++ch) {
        float m = cmin[(p << 3) + ch];
        if (m < best) { best = m; bi = cidx[(p << 3) + ch]; }
    }

    out[OUT_IDX + p] = (float)bi;       // indices output (fp32)

    const float* ev = emb + bi * CDIM;
    const int b  = p >> 12;
    const int hw = p & (HWSZ - 1);
    const float* zp = z + ((size_t)(b * CDIM) << 12) + hw;
    float* zq = out + ((size_t)(b * CDIM) << 12) + hw;

    float ls = 0.0f;
#pragma unroll
    for (int c = 0; c < CDIM; ++c) {
        float e = ev[c];                    // gather: rows hit L1/L2 (256KB table)
        float zv = zp[(size_t)c << 12];
        float d = e - zv;
        ls = fmaf(d, d, ls);
        zq[(size_t)c << 12] = e;            // fp32 z_q, coalesced strided store
    }

    // block reduction -> one atomic per block
#pragma unroll
    for (int off = 32; off > 0; off >>= 1) ls += __shfl_down(ls, off);
    __shared__ float wsum[TPB / 64];
    if ((threadIdx.x & 63) == 0) wsum[threadIdx.x >> 6] = ls;
    __syncthreads();
    if (threadIdx.x == 0) {
        float s = wsum[0] + wsum[1] + wsum[2] + wsum[3];
        atomicAdd(loss_acc, s);
    }
}

// ---------------- Kernel D: scale + emit loss -------------------------------
__global__ void vq_loss_out(const float* __restrict__ loss_acc, float* __restrict__ out) {
    // vq_loss + beta*commitment = (1+0.25) * SSE / numel(z)
    out[OUT_LOSS] = loss_acc[0] * (1.25f / (float)(N_PIX * CDIM));
}

extern "C" void kernel_launch(void* const* d_in, const int* in_sizes, int n_in,
                              void* d_out, int out_size, void* d_ws, size_t ws_size,
                              hipStream_t stream) {
    const float* z   = (const float*)d_in[0];
    const float* emb = (const float*)d_in[1];
    float* ws   = (float*)d_ws;
    float* out  = (float*)d_out;
    float* cmin = ws + OFF_MIN;
    int*   cidx = (int*)(ws + OFF_IDX);
    float* lossp = ws + OFF_LOSS;

    vq_prep<<<dim3(KCODES / TPB), dim3(TPB), 0, stream>>>(emb, ws);
    vq_argmin<<<dim3(N_PIX / TPB, NCHUNK), dim3(TPB), 0, stream>>>(z, ws, emb, cmin, cidx);
    vq_finalize<<<dim3(N_PIX / TPB), dim3(TPB), 0, stream>>>(z, emb, cmin, cidx, out, lossp);
    vq_loss_out<<<1, 1, 0, stream>>>(lossp, out);
}

// Round 12
// 230.627 us; speedup vs baseline: 1.0714x; 1.0714x over previous
//
#include <hip/hip_runtime.h>

// VQ-VAE vector quantization, MI355X gfx950.
// B=16, C=64, H=W=64 -> N=65536 pixels; K=1024 codes, dim 64.
// NUMERICS (DO NOT CHANGE — r7/r9/r11 passed absmax 0.0 with exactly this):
//   nz/ne: numpy pairwise sum, 8-accumulator unroll, products rounded
//          separately (no fma contraction);
//   dot:   single ascending fp32 fma chain per (pixel,code);
//   d = fl( fl(nz - fl(2*dot)) + ne ); strict-< ascending-k tie-break.
//   ~135 pixels are decided by quantized ties.
//
// Perf history:
//   r7 LDS 1px: 161 µs. r8 uniform global: 185. r9 LDS 2px: 137 (= LDS
//   data-path ceiling). r10 SMEM e + SMEM ne: wrong (ne through scalar K$
//   is stale vs prior dispatch's vector stores). r11 SMEM e + LDS ne:
//   correct but 176 µs, VGPR_Count=40 -> the zr[64] ALLOCA WAS NEVER
//   PROMOTED; compiler spills/remats z in the K-loop (scratch traffic).
// r12: zr as 16 named float4 SSA values (no array, no address-taken) +
//      __launch_bounds__(256,4) (VGPR cap 128, need ~85). Fuse: ne computed
//      in-block (identical numpy order), loss emitted by last finalize block
//      (atomic counter) -> 2 dispatches instead of 4.
#define N_PIX   65536
#define CDIM    64
#define KCODES  1024
#define HWSZ    4096          // H*W
#define KCHUNK  128           // codes per argmin block
#define NCHUNK  8             // KCODES / KCHUNK
#define TPB     256

// workspace layout (float-element offsets)
#define OFF_MIN  1024         // 65536*8 f32: per-chunk min score
#define OFF_IDX  525312       // 65536*8 i32: per-chunk argmin
#define OFF_LOSS 1049600      // 1 f32: SSE accumulator
#define OFF_CNT  1049601      // 1 u32: finalize block counter

// output layout (float-element offsets): z_q | indices | loss
#define OUT_IDX  (N_PIX * CDIM)         // 4194304
#define OUT_LOSS (OUT_IDX + N_PIX)      // 4259840

typedef float sf16 __attribute__((ext_vector_type(16)));

// SMEM load: base in SGPR pair, byte offset in SGPR. Explicit waitcnt ties
// the loaded tuples through "+s" so no use can be scheduled before the wait.
#define SLOAD16(dst, base, off) \
    asm volatile("s_load_dwordx16 %0, %1, %2" : "=s"(dst) : "s"(base), "s"(off))
#define SWAIT2(x, y) asm volatile("s_waitcnt lgkmcnt(0)" : "+s"(x), "+s"(y))

// 4 steps of the ascending-k fma chain: one float4 of z against V[o..o+3]
#define FMA4(acc, Q, V, o) \
    acc = fmaf(Q.x, (V)[(o)+0], acc); \
    acc = fmaf(Q.y, (V)[(o)+1], acc); \
    acc = fmaf(Q.z, (V)[(o)+2], acc); \
    acc = fmaf(Q.w, (V)[(o)+3], acc);

// 16 steps (one SGPR 16-tuple) from four named float4s, ascending order
#define STAGE16(acc, V, qa, qb, qc, qd) do { \
    FMA4(acc, qa, V, 0) FMA4(acc, qb, V, 4) FMA4(acc, qc, V, 8) FMA4(acc, qd, V, 12) \
} while (0)

// load one float4 of z (channels c0..c0+3, channel stride 4096 floats)
#define LQ(i, c0) \
    q##i.x = zp[(size_t)((c0)+0) << 12]; \
    q##i.y = zp[(size_t)((c0)+1) << 12]; \
    q##i.z = zp[(size_t)((c0)+2) << 12]; \
    q##i.w = zp[(size_t)((c0)+3) << 12];

// ---------------- Kernel B: argmin (fused ne), SGPR e + named-reg z ---------
// grid = (N_PIX/TPB, NCHUNK); block = TPB. One pixel per thread.
__global__ __launch_bounds__(TPB, 4) void vq_argmin(const float* __restrict__ z,
                                                    const float* __restrict__ emb,
                                                    float* __restrict__ cmin,
                                                    int* __restrict__ cidx,
                                                    float* __restrict__ ws) {
#pragma clang fp contract(off)
    __shared__ float sn[KCHUNK];

    const int chunk = blockIdx.y;
    const int k0 = chunk * KCHUNK;

    // in-block ne: exact numpy pairwise (8-acc, separately-rounded squares)
    if (threadIdx.x < KCHUNK) {
        const float* e = emb + (size_t)(k0 + threadIdx.x) * CDIM;
        float r0 = e[0]*e[0], r1 = e[1]*e[1], r2 = e[2]*e[2], r3 = e[3]*e[3];
        float r4 = e[4]*e[4], r5 = e[5]*e[5], r6 = e[6]*e[6], r7 = e[7]*e[7];
        for (int i = 8; i < CDIM; i += 8) {
            r0 = r0 + e[i+0]*e[i+0]; r1 = r1 + e[i+1]*e[i+1];
            r2 = r2 + e[i+2]*e[i+2]; r3 = r3 + e[i+3]*e[i+3];
            r4 = r4 + e[i+4]*e[i+4]; r5 = r5 + e[i+5]*e[i+5];
            r6 = r6 + e[i+6]*e[i+6]; r7 = r7 + e[i+7]*e[i+7];
        }
        sn[threadIdx.x] = ((r0 + r1) + (r2 + r3)) + ((r4 + r5) + (r6 + r7));
    }
    // zero loss + counter for the (later-dispatched) finalize kernel
    if (blockIdx.x == 0 && chunk == 0 && threadIdx.x == 0) {
        ws[OFF_LOSS] = 0.0f;
        ((unsigned*)(ws + OFF_CNT))[0] = 0u;
    }

    const int p  = blockIdx.x * TPB + threadIdx.x;
    const int b  = p >> 12;
    const int hw = p & (HWSZ - 1);

    // z[b, c, hw]: lanes consecutive in hw -> coalesced; 16 named float4 SSA
    const float* zp = z + ((size_t)(b * CDIM) << 12) + hw;
    float4 q0, q1, q2, q3, q4, q5, q6, q7, q8, q9, q10, q11, q12, q13, q14, q15;
    LQ(0, 0)  LQ(1, 4)  LQ(2, 8)   LQ(3, 12)  LQ(4, 16)  LQ(5, 20)  LQ(6, 24)  LQ(7, 28)
    LQ(8, 32) LQ(9, 36) LQ(10, 40) LQ(11, 44) LQ(12, 48) LQ(13, 52) LQ(14, 56) LQ(15, 60)

    // nz: exact numpy pairwise. r_j accumulates elements i ≡ j (mod 8),
    // ascending i: z[8m+j] = q{2m}.comp(j), z[8m+4+j] = q{2m+1}.comp(j).
    float r0 = q0.x*q0.x, r1 = q0.y*q0.y, r2 = q0.z*q0.z, r3 = q0.w*q0.w;
    float r4 = q1.x*q1.x, r5 = q1.y*q1.y, r6 = q1.z*q1.z, r7 = q1.w*q1.w;
    r0 = r0 + q2.x*q2.x;   r1 = r1 + q2.y*q2.y;   r2 = r2 + q2.z*q2.z;   r3 = r3 + q2.w*q2.w;
    r4 = r4 + q3.x*q3.x;   r5 = r5 + q3.y*q3.y;   r6 = r6 + q3.z*q3.z;   r7 = r7 + q3.w*q3.w;
    r0 = r0 + q4.x*q4.x;   r1 = r1 + q4.y*q4.y;   r2 = r2 + q4.z*q4.z;   r3 = r3 + q4.w*q4.w;
    r4 = r4 + q5.x*q5.x;   r5 = r5 + q5.y*q5.y;   r6 = r6 + q5.z*q5.z;   r7 = r7 + q5.w*q5.w;
    r0 = r0 + q6.x*q6.x;   r1 = r1 + q6.y*q6.y;   r2 = r2 + q6.z*q6.z;   r3 = r3 + q6.w*q6.w;
    r4 = r4 + q7.x*q7.x;   r5 = r5 + q7.y*q7.y;   r6 = r6 + q7.z*q7.z;   r7 = r7 + q7.w*q7.w;
    r0 = r0 + q8.x*q8.x;   r1 = r1 + q8.y*q8.y;   r2 = r2 + q8.z*q8.z;   r3 = r3 + q8.w*q8.w;
    r4 = r4 + q9.x*q9.x;   r5 = r5 + q9.y*q9.y;   r6 = r6 + q9.z*q9.z;   r7 = r7 + q9.w*q9.w;
    r0 = r0 + q10.x*q10.x; r1 = r1 + q10.y*q10.y; r2 = r2 + q10.z*q10.z; r3 = r3 + q10.w*q10.w;
    r4 = r4 + q11.x*q11.x; r5 = r5 + q11.y*q11.y; r6 = r6 + q11.z*q11.z; r7 = r7 + q11.w*q11.w;
    r0 = r0 + q12.x*q12.x; r1 = r1 + q12.y*q12.y; r2 = r2 + q12.z*q12.z; r3 = r3 + q12.w*q12.w;
    r4 = r4 + q13.x*q13.x; r5 = r5 + q13.y*q13.y; r6 = r6 + q13.z*q13.z; r7 = r7 + q13.w*q13.w;
    r0 = r0 + q14.x*q14.x; r1 = r1 + q14.y*q14.y; r2 = r2 + q14.z*q14.z; r3 = r3 + q14.w*q14.w;
    r4 = r4 + q15.x*q15.x; r5 = r5 + q15.y*q15.y; r6 = r6 + q15.z*q15.z; r7 = r7 + q15.w*q15.w;
    const float nz = ((r0 + r1) + (r2 + r3)) + ((r4 + r5) + (r6 + r7));

    __syncthreads();

    const unsigned long long ebase =
        (unsigned long long)(const void*)(emb + (size_t)k0 * CDIM);

    sf16 A0, A1, B0, B1;   // SGPR stage buffers: 16 k-values x 2 codes, x2

    // prime stage 0 of pair kk=0 (codes k0, k0+1; floats [0:16))
    {
        unsigned int o0 = 0u, o1 = 256u;
        SLOAD16(A0, ebase, o0);
        SLOAD16(A1, ebase, o1);
    }

    float best = 3.4e38f;
    int   bi   = k0;
    for (int kk = 0; kk < KCHUNK; kk += 2) {
        const unsigned int po  = (unsigned int)kk * 256u;        // pair byte offset
        const unsigned int npo = (unsigned int)((kk + 2) & (KCHUNK - 1)) * 256u;
        float a0 = 0.f, a1 = 0.f;

        // stage 0: k[0:16)  — consume A, prefetch B(k[16:32))
        SWAIT2(A0, A1);
        SLOAD16(B0, ebase, po + 64u);
        SLOAD16(B1, ebase, po + 320u);
        STAGE16(a0, A0, q0, q1, q2, q3);
        STAGE16(a1, A1, q0, q1, q2, q3);

        // stage 1: k[16:32) — consume B, prefetch A(k[32:48))
        SWAIT2(B0, B1);
        SLOAD16(A0, ebase, po + 128u);
        SLOAD16(A1, ebase, po + 384u);
        STAGE16(a0, B0, q4, q5, q6, q7);
        STAGE16(a1, B1, q4, q5, q6, q7);

        // stage 2: k[32:48) — consume A, prefetch B(k[48:64))
        SWAIT2(A0, A1);
        SLOAD16(B0, ebase, po + 192u);
        SLOAD16(B1, ebase, po + 448u);
        STAGE16(a0, A0, q8, q9, q10, q11);
        STAGE16(a1, A1, q8, q9, q10, q11);

        // stage 3: k[48:64) — consume B, prefetch next pair's stage 0
        SWAIT2(B0, B1);
        SLOAD16(A0, ebase, npo);
        SLOAD16(A1, ebase, npo + 256u);
        STAGE16(a0, B0, q12, q13, q14, q15);
        STAGE16(a1, B1, q12, q13, q14, q15);

        // d = fl( fl(nz - 2*a) + ne ): exact numpy rounding sequence
        float d0 = (nz - 2.0f * a0) + sn[kk];
        float d1 = (nz - 2.0f * a1) + sn[kk + 1];
        if (d0 < best) { best = d0; bi = k0 + kk; }       // strict <, ascending k
        if (d1 < best) { best = d1; bi = k0 + kk + 1; }
    }
    cmin[(p << 3) + chunk] = best;
    cidx[(p << 3) + chunk] = bi;
}

// ---------------- Kernel C: reduce chunks, gather z_q, loss (+emit) ---------
__global__ __launch_bounds__(TPB) void vq_finalize(const float* __restrict__ z,
                                                   const float* __restrict__ emb,
                                                   const float* __restrict__ cmin,
                                                   const int* __restrict__ cidx,
                                                   float* __restrict__ out,
                                                   float* __restrict__ ws) {
    const int p = blockIdx.x * TPB + threadIdx.x;

    // ascending-chunk strict < keeps the earliest (lowest-k) minimum
    float best = cmin[p << 3];
    int   bi   = cidx[p << 3];
#pragma unroll
    for (int ch = 1; ch < NCHUNK; ++ch) {
        float m = cmin[(p << 3) + ch];
        if (m < best) { best = m; bi = cidx[(p << 3) + ch]; }
    }

    out[OUT_IDX + p] = (float)bi;       // indices output (fp32)

    const float* ev = emb + bi * CDIM;
    const int b  = p >> 12;
    const int hw = p & (HWSZ - 1);
    const float* zp = z + ((size_t)(b * CDIM) << 12) + hw;
    float* zq = out + ((size_t)(b * CDIM) << 12) + hw;

    float ls = 0.0f;
#pragma unroll
    for (int c = 0; c < CDIM; ++c) {
        float e = ev[c];                    // gather: rows hit L1/L2 (256KB table)
        float zv = zp[(size_t)c << 12];
        float d = e - zv;
        ls = fmaf(d, d, ls);
        zq[(size_t)c << 12] = e;            // fp32 z_q, coalesced strided store
    }

    // block reduction -> one atomic per block; last block emits the loss
#pragma unroll
    for (int off = 32; off > 0; off >>= 1) ls += __shfl_down(ls, off);
    __shared__ float wsum[TPB / 64];
    if ((threadIdx.x & 63) == 0) wsum[threadIdx.x >> 6] = ls;
    __syncthreads();
    if (threadIdx.x == 0) {
        float s = wsum[0] + wsum[1] + wsum[2] + wsum[3];
        float* lossp = ws + OFF_LOSS;
        atomicAdd(lossp, s);
        __threadfence();                    // make the add visible device-wide
        unsigned old = atomicAdd((unsigned*)(ws + OFF_CNT), 1u);
        if (old == (unsigned)(gridDim.x - 1)) {
            float total = atomicAdd(lossp, 0.0f);   // coherent read via L2 atomic
            // vq_loss + beta*commitment = (1+0.25) * SSE / numel(z)
            out[OUT_LOSS] = total * (1.25f / (float)(N_PIX * CDIM));
        }
    }
}

extern "C" void kernel_launch(void* const* d_in, const int* in_sizes, int n_in,
                              void* d_out, int out_size, void* d_ws, size_t ws_size,
                              hipStream_t stream) {
    const float* z   = (const float*)d_in[0];
    const float* emb = (const float*)d_in[1];
    float* ws   = (float*)d_ws;
    float* out  = (float*)d_out;
    float* cmin = ws + OFF_MIN;
    int*   cidx = (int*)(ws + OFF_IDX);

    vq_argmin<<<dim3(N_PIX / TPB, NCHUNK), dim3(TPB), 0, stream>>>(z, emb, cmin, cidx, ws);
    vq_finalize<<<dim3(N_PIX / TPB), dim3(TPB), 0, stream>>>(z, emb, cmin, cidx, out, ws);
}

// Round 14
// 227.795 us; speedup vs baseline: 1.0847x; 1.0124x over previous
//
#include <hip/hip_runtime.h>

// VQ-VAE vector quantization, MI355X gfx950.
// B=16, C=64, H=W=64 -> N=65536 pixels; K=1024 codes, dim 64.
// NUMERICS (DO NOT CHANGE — r7/r9/r11/r12 passed absmax 0.0 with exactly this):
//   nz/ne: numpy pairwise sum, 8-accumulator unroll, products rounded
//          separately (no fma contraction);
//   dot:   single ascending fp32 fma chain per (pixel,code);
//   d = fl( fl(nz - fl(2*dot)) + ne ); strict-< ascending-k tie-break.
//   ~135 pixels are decided by quantized ties.
//
// Perf history:
//   r7 LDS 1px: 161 µs. r8 uniform global: 185. r9 LDS 2px: 137 (LDS
//   data-path ceiling ~63 TB/s). r10 SMEM ne: stale-K$ corruption. r11 SMEM
//   e + LDS ne: 176, VGPR=40. r12 named float4 SSA: 165, VGPR STILL 40 —
//   the compiler REMATERIALIZES the invariant z loads inside the K-loop
//   (FMA only ~40% of VALU issue; 54.6 µs FMA floor vs 165 measured).
//   r13: float4-tied "+v" pin -> LLVM compile error ("tied indirect register
//   inputs"). r14: pin the four SCALAR components instead (supported form).
#define N_PIX   65536
#define CDIM    64
#define KCODES  1024
#define HWSZ    4096          // H*W
#define KCHUNK  128           // codes per argmin block
#define NCHUNK  8             // KCODES / KCHUNK
#define TPB     256

// workspace layout (float-element offsets)
#define OFF_MIN  1024         // 65536*8 f32: per-chunk min score
#define OFF_IDX  525312       // 65536*8 i32: per-chunk argmin
#define OFF_LOSS 1049600      // 1 f32: SSE accumulator
#define OFF_CNT  1049601      // 1 u32: finalize block counter

// output layout (float-element offsets): z_q | indices | loss
#define OUT_IDX  (N_PIX * CDIM)         // 4194304
#define OUT_LOSS (OUT_IDX + N_PIX)      // 4259840

typedef float sf16 __attribute__((ext_vector_type(16)));

// SMEM load: base in SGPR pair, byte offset in SGPR. Explicit waitcnt ties
// the loaded tuples through "+s" so no use can be scheduled before the wait.
#define SLOAD16(dst, base, off) \
    asm volatile("s_load_dwordx16 %0, %1, %2" : "=s"(dst) : "s"(base), "s"(off))
#define SWAIT2(x, y) asm volatile("s_waitcnt lgkmcnt(0)" : "+s"(x), "+s"(y))

// opaque register pin: emits nothing, kills rematerialization of the loads.
// Scalar component ties (r13's float4 tie is unsupported by the backend).
#define PIN4(v) asm volatile("" : "+v"(v.x), "+v"(v.y), "+v"(v.z), "+v"(v.w))

// 4 steps of the ascending-k fma chain: one float4 of z against V[o..o+3]
#define FMA4(acc, Q, V, o) \
    acc = fmaf(Q.x, (V)[(o)+0], acc); \
    acc = fmaf(Q.y, (V)[(o)+1], acc); \
    acc = fmaf(Q.z, (V)[(o)+2], acc); \
    acc = fmaf(Q.w, (V)[(o)+3], acc);

// 16 steps (one SGPR 16-tuple) from four named float4s, ascending order
#define STAGE16(acc, V, qa, qb, qc, qd) do { \
    FMA4(acc, qa, V, 0) FMA4(acc, qb, V, 4) FMA4(acc, qc, V, 8) FMA4(acc, qd, V, 12) \
} while (0)

// load one float4 of z (channels c0..c0+3, channel stride 4096 floats)
#define LQ(i, c0) \
    q##i.x = zp[(size_t)((c0)+0) << 12]; \
    q##i.y = zp[(size_t)((c0)+1) << 12]; \
    q##i.z = zp[(size_t)((c0)+2) << 12]; \
    q##i.w = zp[(size_t)((c0)+3) << 12];

// ---------------- Kernel B: argmin (fused ne), SGPR e + pinned-reg z --------
// grid = (N_PIX/TPB, NCHUNK); block = TPB. One pixel per thread.
__global__ __launch_bounds__(TPB, 4) void vq_argmin(const float* __restrict__ z,
                                                    const float* __restrict__ emb,
                                                    float* __restrict__ cmin,
                                                    int* __restrict__ cidx,
                                                    float* __restrict__ ws) {
#pragma clang fp contract(off)
    __shared__ float sn[KCHUNK];

    const int chunk = blockIdx.y;
    const int k0 = chunk * KCHUNK;

    // in-block ne: exact numpy pairwise (8-acc, separately-rounded squares)
    if (threadIdx.x < KCHUNK) {
        const float* e = emb + (size_t)(k0 + threadIdx.x) * CDIM;
        float r0 = e[0]*e[0], r1 = e[1]*e[1], r2 = e[2]*e[2], r3 = e[3]*e[3];
        float r4 = e[4]*e[4], r5 = e[5]*e[5], r6 = e[6]*e[6], r7 = e[7]*e[7];
        for (int i = 8; i < CDIM; i += 8) {
            r0 = r0 + e[i+0]*e[i+0]; r1 = r1 + e[i+1]*e[i+1];
            r2 = r2 + e[i+2]*e[i+2]; r3 = r3 + e[i+3]*e[i+3];
            r4 = r4 + e[i+4]*e[i+4]; r5 = r5 + e[i+5]*e[i+5];
            r6 = r6 + e[i+6]*e[i+6]; r7 = r7 + e[i+7]*e[i+7];
        }
        sn[threadIdx.x] = ((r0 + r1) + (r2 + r3)) + ((r4 + r5) + (r6 + r7));
    }
    // zero loss + counter for the (later-dispatched) finalize kernel
    if (blockIdx.x == 0 && chunk == 0 && threadIdx.x == 0) {
        ws[OFF_LOSS] = 0.0f;
        ((unsigned*)(ws + OFF_CNT))[0] = 0u;
    }

    const int p  = blockIdx.x * TPB + threadIdx.x;
    const int b  = p >> 12;
    const int hw = p & (HWSZ - 1);

    // z[b, c, hw]: lanes consecutive in hw -> coalesced; 16 pinned float4s
    const float* zp = z + ((size_t)(b * CDIM) << 12) + hw;
    float4 q0, q1, q2, q3, q4, q5, q6, q7, q8, q9, q10, q11, q12, q13, q14, q15;
    LQ(0, 0)  LQ(1, 4)  LQ(2, 8)   LQ(3, 12)  LQ(4, 16)  LQ(5, 20)  LQ(6, 24)  LQ(7, 28)
    LQ(8, 32) LQ(9, 36) LQ(10, 40) LQ(11, 44) LQ(12, 48) LQ(13, 52) LQ(14, 56) LQ(15, 60)
    PIN4(q0);  PIN4(q1);  PIN4(q2);  PIN4(q3);
    PIN4(q4);  PIN4(q5);  PIN4(q6);  PIN4(q7);
    PIN4(q8);  PIN4(q9);  PIN4(q10); PIN4(q11);
    PIN4(q12); PIN4(q13); PIN4(q14); PIN4(q15);

    // nz: exact numpy pairwise. r_j accumulates elements i ≡ j (mod 8),
    // ascending i: z[8m+j] = q{2m}.comp(j), z[8m+4+j] = q{2m+1}.comp(j).
    float r0 = q0.x*q0.x, r1 = q0.y*q0.y, r2 = q0.z*q0.z, r3 = q0.w*q0.w;
    float r4 = q1.x*q1.x, r5 = q1.y*q1.y, r6 = q1.z*q1.z, r7 = q1.w*q1.w;
    r0 = r0 + q2.x*q2.x;   r1 = r1 + q2.y*q2.y;   r2 = r2 + q2.z*q2.z;   r3 = r3 + q2.w*q2.w;
    r4 = r4 + q3.x*q3.x;   r5 = r5 + q3.y*q3.y;   r6 = r6 + q3.z*q3.z;   r7 = r7 + q3.w*q3.w;
    r0 = r0 + q4.x*q4.x;   r1 = r1 + q4.y*q4.y;   r2 = r2 + q4.z*q4.z;   r3 = r3 + q4.w*q4.w;
    r4 = r4 + q5.x*q5.x;   r5 = r5 + q5.y*q5.y;   r6 = r6 + q5.z*q5.z;   r7 = r7 + q5.w*q5.w;
    r0 = r0 + q6.x*q6.x;   r1 = r1 + q6.y*q6.y;   r2 = r2 + q6.z*q6.z;   r3 = r3 + q6.w*q6.w;
    r4 = r4 + q7.x*q7.x;   r5 = r5 + q7.y*q7.y;   r6 = r6 + q7.z*q7.z;   r7 = r7 + q7.w*q7.w;
    r0 = r0 + q8.x*q8.x;   r1 = r1 + q8.y*q8.y;   r2 = r2 + q8.z*q8.z;   r3 = r3 + q8.w*q8.w;
    r4 = r4 + q9.x*q9.x;   r5 = r5 + q9.y*q9.y;   r6 = r6 + q9.z*q9.z;   r7 = r7 + q9.w*q9.w;
    r0 = r0 + q10.x*q10.x; r1 = r1 + q10.y*q10.y; r2 = r2 + q10.z*q10.z; r3 = r3 + q10.w*q10.w;
    r4 = r4 + q11.x*q11.x; r5 = r5 + q11.y*q11.y; r6 = r6 + q11.z*q11.z; r7 = r7 + q11.w*q11.w;
    r0 = r0 + q12.x*q12.x; r1 = r1 + q12.y*q12.y; r2 = r2 + q12.z*q12.z; r3 = r3 + q12.w*q12.w;
    r4 = r4 + q13.x*q13.x; r5 = r5 + q13.y*q13.y; r6 = r6 + q13.z*q13.z; r7 = r7 + q13.w*q13.w;
    r0 = r0 + q14.x*q14.x; r1 = r1 + q14.y*q14.y; r2 = r2 + q14.z*q14.z; r3 = r3 + q14.w*q14.w;
    r4 = r4 + q15.x*q15.x; r5 = r5 + q15.y*q15.y; r6 = r6 + q15.z*q15.z; r7 = r7 + q15.w*q15.w;
    const float nz = ((r0 + r1) + (r2 + r3)) + ((r4 + r5) + (r6 + r7));

    __syncthreads();

    const unsigned long long ebase =
        (unsigned long long)(const void*)(emb + (size_t)k0 * CDIM);

    sf16 A0, A1, B0, B1;   // SGPR stage buffers: 16 k-values x 2 codes, x2

    // prime stage 0 of pair kk=0 (codes k0, k0+1; floats [0:16))
    {
        unsigned int o0 = 0u, o1 = 256u;
        SLOAD16(A0, ebase, o0);
        SLOAD16(A1, ebase, o1);
    }

    float best = 3.4e38f;
    int   bi   = k0;
    for (int kk = 0; kk < KCHUNK; kk += 2) {
        const unsigned int po  = (unsigned int)kk * 256u;        // pair byte offset
        const unsigned int npo = (unsigned int)((kk + 2) & (KCHUNK - 1)) * 256u;
        float a0 = 0.f, a1 = 0.f;

        // stage 0: k[0:16)  — consume A, prefetch B(k[16:32))
        SWAIT2(A0, A1);
        SLOAD16(B0, ebase, po + 64u);
        SLOAD16(B1, ebase, po + 320u);
        STAGE16(a0, A0, q0, q1, q2, q3);
        STAGE16(a1, A1, q0, q1, q2, q3);

        // stage 1: k[16:32) — consume B, prefetch A(k[32:48))
        SWAIT2(B0, B1);
        SLOAD16(A0, ebase, po + 128u);
        SLOAD16(A1, ebase, po + 384u);
        STAGE16(a0, B0, q4, q5, q6, q7);
        STAGE16(a1, B1, q4, q5, q6, q7);

        // stage 2: k[32:48) — consume A, prefetch B(k[48:64))
        SWAIT2(A0, A1);
        SLOAD16(B0, ebase, po + 192u);
        SLOAD16(B1, ebase, po + 448u);
        STAGE16(a0, A0, q8, q9, q10, q11);
        STAGE16(a1, A1, q8, q9, q10, q11);

        // stage 3: k[48:64) — consume B, prefetch next pair's stage 0
        SWAIT2(B0, B1);
        SLOAD16(A0, ebase, npo);
        SLOAD16(A1, ebase, npo + 256u);
        STAGE16(a0, B0, q12, q13, q14, q15);
        STAGE16(a1, B1, q12, q13, q14, q15);

        // d = fl( fl(nz - 2*a) + ne ): exact numpy rounding sequence
        float d0 = (nz - 2.0f * a0) + sn[kk];
        float d1 = (nz - 2.0f * a1) + sn[kk + 1];
        if (d0 < best) { best = d0; bi = k0 + kk; }       // strict <, ascending k
        if (d1 < best) { best = d1; bi = k0 + kk + 1; }
    }
    cmin[(p << 3) + chunk] = best;
    cidx[(p << 3) + chunk] = bi;
}

// ---------------- Kernel C: reduce chunks, gather z_q, loss (+emit) ---------
__global__ __launch_bounds__(TPB) void vq_finalize(const float* __restrict__ z,
                                                   const float* __restrict__ emb,
                                                   const float* __restrict__ cmin,
                                                   const int* __restrict__ cidx,
                                                   float* __restrict__ out,
                                                   float* __restrict__ ws) {
    const int p = blockIdx.x * TPB + threadIdx.x;

    // ascending-chunk strict < keeps the earliest (lowest-k) minimum
    float best = cmin[p << 3];
    int   bi   = cidx[p << 3];
#pragma unroll
    for (int ch = 1; ch < NCHUNK; ++ch) {
        float m = cmin[(p << 3) + ch];
        if (m < best) { best = m; bi = cidx[(p << 3) + ch]; }
    }

    out[OUT_IDX + p] = (float)bi;       // indices output (fp32)

    const int b  = p >> 12;
    const int hw = p & (HWSZ - 1);
    const float* zp = z + ((size_t)(b * CDIM) << 12) + hw;
    float* zq = out + ((size_t)(b * CDIM) << 12) + hw;

    // vectorized gather: emb row is 256 B aligned -> 16 x dwordx4
    const float4* ev4 = (const float4*)(emb + (size_t)bi * CDIM);
    float ls = 0.0f;
#pragma unroll
    for (int c4 = 0; c4 < CDIM / 4; ++c4) {
        float4 e4 = ev4[c4];
        const int c = c4 * 4;
        float zv0 = zp[(size_t)(c + 0) << 12];
        float zv1 = zp[(size_t)(c + 1) << 12];
        float zv2 = zp[(size_t)(c + 2) << 12];
        float zv3 = zp[(size_t)(c + 3) << 12];
        float d0 = e4.x - zv0, d1 = e4.y - zv1, d2 = e4.z - zv2, d3 = e4.w - zv3;
        ls = fmaf(d0, d0, ls); ls = fmaf(d1, d1, ls);
        ls = fmaf(d2, d2, ls); ls = fmaf(d3, d3, ls);
        zq[(size_t)(c + 0) << 12] = e4.x;
        zq[(size_t)(c + 1) << 12] = e4.y;
        zq[(size_t)(c + 2) << 12] = e4.z;
        zq[(size_t)(c + 3) << 12] = e4.w;
    }

    // block reduction -> one atomic per block; last block emits the loss
#pragma unroll
    for (int off = 32; off > 0; off >>= 1) ls += __shfl_down(ls, off);
    __shared__ float wsum[TPB / 64];
    if ((threadIdx.x & 63) == 0) wsum[threadIdx.x >> 6] = ls;
    __syncthreads();
    if (threadIdx.x == 0) {
        float s = wsum[0] + wsum[1] + wsum[2] + wsum[3];
        float* lossp = ws + OFF_LOSS;
        atomicAdd(lossp, s);
        __threadfence();                    // make the add visible device-wide
        unsigned old = atomicAdd((unsigned*)(ws + OFF_CNT), 1u);
        if (old == (unsigned)(gridDim.x - 1)) {
            float total = atomicAdd(lossp, 0.0f);   // coherent read via L2 atomic
            // vq_loss + beta*commitment = (1+0.25) * SSE / numel(z)
            out[OUT_LOSS] = total * (1.25f / (float)(N_PIX * CDIM));
        }
    }
}

extern "C" void kernel_launch(void* const* d_in, const int* in_sizes, int n_in,
                              void* d_out, int out_size, void* d_ws, size_t ws_size,
                              hipStream_t stream) {
    const float* z   = (const float*)d_in[0];
    const float* emb = (const float*)d_in[1];
    float* ws   = (float*)d_ws;
    float* out  = (float*)d_out;
    float* cmin = ws + OFF_MIN;
    int*   cidx = (int*)(ws + OFF_IDX);

    vq_argmin<<<dim3(N_PIX / TPB, NCHUNK), dim3(TPB), 0, stream>>>(z, emb, cmin, cidx, ws);
    vq_finalize<<<dim3(N_PIX / TPB), dim3(TPB), 0, stream>>>(z, emb, cmin, cidx, out, ws);
}